// Round 15
// baseline (1522.712 us; speedup 1.0000x reference)
//
#include <hip/hip_runtime.h>
#include <math.h>

#define S_LEN 2048
#define DMODEL 2048
#define NHEAD 16
#define KVHEAD 2
#define DHEAD 128
#define NLAYER 4
#define VOCAB 10000
#define INNER_DIM 8192
#define LN_EPS 1e-5f
#define VOCAB_PAD 10240
#define QKVN 2560

typedef __attribute__((ext_vector_type(4))) float f32x4;
typedef __attribute__((ext_vector_type(2))) float f32x2;
typedef __attribute__((ext_vector_type(8))) short s16x8;
typedef __attribute__((ext_vector_type(4))) short s16x4;

__device__ __forceinline__ short f2bf(float f) {
  union { float f; unsigned u; } v; v.f = f;
  unsigned r = v.u + 0x7FFFu + ((v.u >> 16) & 1u);  // RNE
  return (short)(r >> 16);
}
__device__ __forceinline__ float bf2f(short s) {
  union { unsigned u; float f; } v; v.u = ((unsigned)(unsigned short)s) << 16;
  return v.f;
}

__device__ __forceinline__ float gelu_tanh(float x) {
  float z = 0.7978845608028654f * (x + 0.044715f * x * x * x);
  float t = __expf(-2.0f * fabsf(z));
  float th = (1.0f - t) / (1.0f + t);
  th = copysignf(th, z);
  return 0.5f * x * (1.0f + th);
}

__device__ __forceinline__ void glds16(const void* g, void* l) {
  __builtin_amdgcn_global_load_lds(
      (const __attribute__((address_space(1))) unsigned int*)g,
      (__attribute__((address_space(3))) unsigned int*)l, 16, 0, 0);
}

// ---------------- ALL per-layer weight transposes in one launch ----------
__global__ __launch_bounds__(256)
void wtrans_all(const float* __restrict__ wq, const float* __restrict__ wk,
                const float* __restrict__ wv, const float* __restrict__ wo,
                const float* __restrict__ w1, const float* __restrict__ w2,
                short* __restrict__ wqkvT, short* __restrict__ woT,
                short* __restrict__ w1T, short* __restrict__ w2T) {
  __shared__ float ld[64][65];
  int b = blockIdx.x;
  const float* W; short* WT; int gx, K;
  if (b < 1024)      { W = wq; WT = wqkvT; gx = 32; K = 2048; }
  else if (b < 1152) { b -= 1024; W = wk; WT = wqkvT + (size_t)2048 * 2048; gx = 4; K = 2048; }
  else if (b < 1280) { b -= 1152; W = wv; WT = wqkvT + (size_t)2304 * 2048; gx = 4; K = 2048; }
  else if (b < 2304) { b -= 1280; W = wo; WT = woT; gx = 32; K = 2048; }
  else if (b < 6400) { b -= 2304; W = w1; WT = w1T; gx = 128; K = 2048; }
  else               { b -= 6400; W = w2; WT = w2T; gx = 32; K = 8192; }
  const int N = gx * 64;
  const int n0 = (b % gx) * 64, k0 = (b / gx) * 64;
  const int tid = threadIdx.x;
  const int rbase = tid >> 4;
  const int c4 = (tid & 15) * 4;
#pragma unroll
  for (int q = 0; q < 4; ++q) {
    int kk = rbase + q * 16;
    f32x4 v = *(const f32x4*)(W + (size_t)(k0 + kk) * N + n0 + c4);
    ld[kk][c4 + 0] = v[0]; ld[kk][c4 + 1] = v[1];
    ld[kk][c4 + 2] = v[2]; ld[kk][c4 + 3] = v[3];
  }
  __syncthreads();
#pragma unroll
  for (int s = 0; s < 2; ++s) {
    int lin = tid + s * 256;
    int nn = lin >> 3;
    int ks = lin & 7;
    s16x8 o;
#pragma unroll
    for (int j = 0; j < 8; ++j) o[j] = f2bf(ld[ks * 8 + j][nn]);
    *(s16x8*)&WT[(size_t)(n0 + nn) * K + k0 + ks * 8] = o;
  }
}

// ---------------- head weight transpose (edge at N=10000) ----------------
__global__ __launch_bounds__(256)
void wtrans64(const float* __restrict__ W, short* __restrict__ WT,
              int K, int N, int NP) {
  __shared__ float ld[64][65];
  const int n0 = blockIdx.x * 64, k0 = blockIdx.y * 64;
  const int tid = threadIdx.x;
  const int rbase = tid >> 4;
  const int c4 = (tid & 15) * 4;
#pragma unroll
  for (int q = 0; q < 4; ++q) {
    int kk = rbase + q * 16;
    const float* wp = W + (size_t)(k0 + kk) * N + n0 + c4;
    float v0, v1, v2, v3;
    if (n0 + c4 + 3 < N) {
      f32x4 v = *(const f32x4*)wp;
      v0 = v[0]; v1 = v[1]; v2 = v[2]; v3 = v[3];
    } else {
      v0 = (n0 + c4 + 0 < N) ? wp[0] : 0.f;
      v1 = (n0 + c4 + 1 < N) ? wp[1] : 0.f;
      v2 = (n0 + c4 + 2 < N) ? wp[2] : 0.f;
      v3 = (n0 + c4 + 3 < N) ? wp[3] : 0.f;
    }
    ld[kk][c4 + 0] = v0; ld[kk][c4 + 1] = v1;
    ld[kk][c4 + 2] = v2; ld[kk][c4 + 3] = v3;
  }
  __syncthreads();
#pragma unroll
  for (int s = 0; s < 2; ++s) {
    int lin = tid + s * 256;
    int nn = lin >> 3;
    int ks = lin & 7;
    int n = n0 + nn;
    if (n < NP) {
      s16x8 o;
#pragma unroll
      for (int j = 0; j < 8; ++j)
        o[j] = (n < N) ? f2bf(ld[ks * 8 + j][nn]) : (short)0;
      *(s16x8*)&WT[(size_t)n * K + k0 + ks * 8] = o;
    }
  }
}

// ---------------- LN core: 3 rounds (hb bf16) ----------------
__device__ __forceinline__ void ln3_core(
    float (&v)[8], int tid, int wave,
    const float* __restrict__ mg, const float* __restrict__ mb,
    const float* __restrict__ bg, const float* __restrict__ bb,
    const float* __restrict__ ag, const float* __restrict__ ab,
    short* __restrict__ hbrow, short* __restrict__ hnrow,
    float rs[3][4], float rs2[3][4]) {
#pragma unroll
  for (int rnd = 0; rnd < 3; ++rnd) {
    float s = 0.f, s2 = 0.f;
#pragma unroll
    for (int i = 0; i < 8; ++i) { s += v[i]; s2 += v[i] * v[i]; }
#pragma unroll
    for (int off = 1; off < 64; off <<= 1) {
      s += __shfl_xor(s, off); s2 += __shfl_xor(s2, off);
    }
    if ((tid & 63) == 0) { rs[rnd][wave] = s; rs2[rnd][wave] = s2; }
    __syncthreads();
    s = rs[rnd][0] + rs[rnd][1] + rs[rnd][2] + rs[rnd][3];
    s2 = rs2[rnd][0] + rs2[rnd][1] + rs2[rnd][2] + rs2[rnd][3];
    const float mean = s * (1.f / DMODEL);
    const float var = s2 * (1.f / DMODEL) - mean * mean;
    const float rstd = rsqrtf(var + LN_EPS);
    const float* gg = (rnd == 0) ? mg : (rnd == 1) ? bg : ag;
    const float* bbv = (rnd == 0) ? mb : (rnd == 1) ? bb : ab;
#pragma unroll
    for (int i = 0; i < 8; ++i) {
      int idx = tid + i * 256;
      v[i] = (v[i] - mean) * rstd * gg[idx] + bbv[idx];
    }
    if (rnd == 1) {
#pragma unroll
      for (int i = 0; i < 8; ++i) hbrow[tid + i * 256] = f2bf(v[i]);
    }
  }
#pragma unroll
  for (int i = 0; i < 8; ++i) hnrow[tid + i * 256] = f2bf(v[i]);
}

__global__ __launch_bounds__(256)
void embed_ln3(const int* __restrict__ text, const float* __restrict__ ew,
               const float* __restrict__ mg, const float* __restrict__ mb,
               const float* __restrict__ bg, const float* __restrict__ bb,
               const float* __restrict__ ag, const float* __restrict__ ab,
               short* __restrict__ hb16, short* __restrict__ hn16) {
  const int row = blockIdx.x;
  const int tid = threadIdx.x;
  const int wave = tid >> 6;
  __shared__ float rs[3][4], rs2[3][4];
  float v[8];
  const float* x = ew + (size_t)text[row] * DMODEL;
#pragma unroll
  for (int i = 0; i < 8; ++i) v[i] = x[tid + i * 256];
  ln3_core(v, tid, wave, mg, mb, bg, bb, ag, ab,
           hb16 + (size_t)row * DMODEL, hn16 + (size_t)row * DMODEL, rs, rs2);
}

__global__ __launch_bounds__(256)
void ln_triple_sum(const float* __restrict__ p0, const float* __restrict__ p1,
                   const short* __restrict__ h216, const float* __restrict__ b2,
                   const float* __restrict__ mg, const float* __restrict__ mb,
                   const float* __restrict__ bg, const float* __restrict__ bb,
                   const float* __restrict__ ag, const float* __restrict__ ab,
                   short* __restrict__ hb16, short* __restrict__ hn16) {
  const int row = blockIdx.x;
  const int tid = threadIdx.x;
  const int wave = tid >> 6;
  __shared__ float rs[3][4], rs2[3][4];
  float v[8];
  const size_t base = (size_t)row * DMODEL;
#pragma unroll
  for (int i = 0; i < 8; ++i) {
    int idx = tid + i * 256;
    v[i] = p0[base + idx] + p1[base + idx] + b2[idx] + bf2f(h216[base + idx]);
  }
  ln3_core(v, tid, wave, mg, mb, bg, bb, ag, ab,
           hb16 + base, hn16 + base, rs, rs2);
}

__global__ __launch_bounds__(256)
void ln_dual_sum(const float* __restrict__ p0, const float* __restrict__ p1,
                 const short* __restrict__ h216, const float* __restrict__ b2,
                 const float* __restrict__ mg, const float* __restrict__ mb,
                 const float* __restrict__ hg, const float* __restrict__ hbv,
                 short* __restrict__ out16) {
  const int row = blockIdx.x;
  const int tid = threadIdx.x;
  const int wave = tid >> 6;
  __shared__ float rs[2][4], rs2[2][4];
  float v[8];
  const size_t base = (size_t)row * DMODEL;
#pragma unroll
  for (int i = 0; i < 8; ++i) {
    int idx = tid + i * 256;
    v[i] = p0[base + idx] + p1[base + idx] + b2[idx] + bf2f(h216[base + idx]);
  }
#pragma unroll
  for (int rnd = 0; rnd < 2; ++rnd) {
    float s = 0.f, s2 = 0.f;
#pragma unroll
    for (int i = 0; i < 8; ++i) { s += v[i]; s2 += v[i] * v[i]; }
#pragma unroll
    for (int off = 1; off < 64; off <<= 1) {
      s += __shfl_xor(s, off); s2 += __shfl_xor(s2, off);
    }
    if ((tid & 63) == 0) { rs[rnd][wave] = s; rs2[rnd][wave] = s2; }
    __syncthreads();
    s = rs[rnd][0] + rs[rnd][1] + rs[rnd][2] + rs[rnd][3];
    s2 = rs2[rnd][0] + rs2[rnd][1] + rs2[rnd][2] + rs2[rnd][3];
    const float mean = s * (1.f / DMODEL);
    const float var = s2 * (1.f / DMODEL) - mean * mean;
    const float rstd = rsqrtf(var + LN_EPS);
    const float* gg = (rnd == 0) ? mg : hg;
    const float* bbv = (rnd == 0) ? mb : hbv;
#pragma unroll
    for (int i = 0; i < 8; ++i) {
      int idx = tid + i * 256;
      v[i] = (v[i] - mean) * rstd * gg[idx] + bbv[idx];
    }
  }
  short* o = out16 + base;
#pragma unroll
  for (int i = 0; i < 8; ++i) o[tid + i * 256] = f2bf(v[i]);
}

// ---------------- SINGLE-buffered bf16 GEMM (m97 structure) --------------
// Per K-step: barrier (prior reads done) -> stage -> vmcnt(0)+barrier ->
// full-tile ds_read + MFMA. 32/24 KB LDS -> ~3 blocks/CU; cross-block wave
// overlap hides the drain (m114). BM may differ from BN; optional split-K.
template<int BM, int BN, int BK, int WM, int WN, int ACT, bool BIAS, bool RESB,
         bool WF, bool WB, bool SPLITK>
__global__ __launch_bounds__(WM * WN * 64)
void gemm_sb(const short* __restrict__ A, const short* __restrict__ BT,
             const float* __restrict__ bias, const short* __restrict__ res16,
             float* __restrict__ Cf, short* __restrict__ Cb,
             int M, int N, int K, int LDA, int LDB) {
  constexpr int THREADS = WM * WN * 64;
  constexpr int MR = BM / WM / 16;
  constexpr int NR = BN / WN / 16;
  constexpr int KH = BK / 32;
  constexpr int SLOTS = BK / 8;
  constexpr int SMASK = SLOTS - 1;
  constexpr int RSH = (SLOTS == 8) ? 0 : 1;
  constexpr int CSH = (SLOTS == 8) ? 3 : 2;
  constexpr int NIA = (BM * BK) / (THREADS * 8);
  constexpr int NIB = (BN * BK) / (THREADS * 8);
  __shared__ short As[BM * BK];
  __shared__ short Bs[BN * BK];
  const int tid = threadIdx.x;
  const int wave = tid >> 6, lane = tid & 63;
  const int g = lane >> 4, r = lane & 15;
  const int wm = wave / WN, wn = wave % WN;
  const int zoff = SPLITK ? blockIdx.z * K : 0;
  if (SPLITK && WF) Cf += (size_t)blockIdx.z * M * N;

  const int GY = gridDim.y;
  int lin = blockIdx.x + blockIdx.y * gridDim.x;
  int nwg = gridDim.x * GY;
  int sw = ((nwg & 7) == 0) ? ((lin & 7) * (nwg >> 3) + (lin >> 3)) : lin;
  const int bm = (sw % GY) * BM;
  const int bn = (sw / GY) * BN;

  const short* gsrc[NIA + NIB];
  short* ldst[NIA + NIB];
#pragma unroll
  for (int i = 0; i < NIA; ++i) {
    int c = i * THREADS + tid;
    int row = c >> CSH;
    int slot = c & SMASK;
    int col = ((slot ^ ((row >> RSH) & SMASK)) << 3);
    gsrc[i] = A + (size_t)(bm + row) * LDA + zoff + col;
    ldst[i] = &As[(i * THREADS + (wave << 6)) << 3];
  }
#pragma unroll
  for (int i = 0; i < NIB; ++i) {
    int c = i * THREADS + tid;
    int row = c >> CSH;
    int slot = c & SMASK;
    int col = ((slot ^ ((row >> RSH) & SMASK)) << 3);
    gsrc[NIA + i] = BT + (size_t)(bn + row) * LDB + zoff + col;
    ldst[NIA + i] = &Bs[(i * THREADS + (wave << 6)) << 3];
  }

  f32x4 acc[MR][NR] = {};
  const int NT = K / BK;

  for (int t = 0; t < NT; ++t) {
    if (t) __syncthreads();   // prior tile's LDS reads complete
#pragma unroll
    for (int i = 0; i < NIA + NIB; ++i) glds16(gsrc[i] + t * BK, ldst[i]);
    asm volatile("s_waitcnt vmcnt(0)" ::: "memory");
    __syncthreads();          // all waves' stagings landed
    s16x8 af[MR][KH], bf[NR][KH];
#pragma unroll
    for (int m = 0; m < MR; ++m) {
      int rr = wm * (MR * 16) + m * 16 + r;
#pragma unroll
      for (int kk = 0; kk < KH; ++kk) {
        int lg = kk * 4 + g;
        af[m][kk] = *(const s16x8*)&As[rr * BK + ((lg ^ ((rr >> RSH) & SMASK)) << 3)];
      }
    }
#pragma unroll
    for (int n = 0; n < NR; ++n) {
      int rr = wn * (NR * 16) + n * 16 + r;
#pragma unroll
      for (int kk = 0; kk < KH; ++kk) {
        int lg = kk * 4 + g;
        bf[n][kk] = *(const s16x8*)&Bs[rr * BK + ((lg ^ ((rr >> RSH) & SMASK)) << 3)];
      }
    }
#pragma unroll
    for (int m = 0; m < MR; ++m)
#pragma unroll
      for (int n = 0; n < NR; ++n)
#pragma unroll
        for (int kk = 0; kk < KH; ++kk)
          acc[m][n] = __builtin_amdgcn_mfma_f32_16x16x32_bf16(af[m][kk], bf[n][kk], acc[m][n], 0, 0, 0);
  }

#pragma unroll
  for (int m = 0; m < MR; ++m) {
    int row = bm + wm * (MR * 16) + m * 16 + g * 4;
#pragma unroll
    for (int n = 0; n < NR; ++n) {
      int col = bn + wn * (NR * 16) + n * 16 + r;
      if (col < N) {
#pragma unroll
        for (int j = 0; j < 4; ++j) {
          float v = acc[m][n][j];
          if (BIAS) v += bias[col];
          if (ACT) v = gelu_tanh(v);
          if (RESB) v += bf2f(res16[(size_t)(row + j) * N + col]);
          if (WF) Cf[(size_t)(row + j) * N + col] = v;
          if (WB) Cb[(size_t)(row + j) * N + col] = f2bf(v);
        }
      }
    }
  }
}

// ---------------- qkv GEMM: single-buffered 64x128, fused epilogues ------
__global__ __launch_bounds__(256)
void gemm_qkv(const short* __restrict__ A, const short* __restrict__ BT,
              const float* __restrict__ qg, const float* __restrict__ kg,
              short* __restrict__ qb, short* __restrict__ kb,
              short* __restrict__ vt, int M, int K) {
  __shared__ short As[64 * 64];     // 8 KB
  __shared__ short Bs[128 * 64];    // 16 KB (also V-transpose scratch)
  __shared__ float rsm[2][64], rs2m[2][64];
  const int tid = threadIdx.x;
  const int wave = tid >> 6, lane = tid & 63;
  const int g = lane >> 4, r = lane & 15;
  const int wm = wave >> 1, wn = wave & 1;   // 2x2 waves: 32-row x 64-col

  const int GY = gridDim.y;  // 32
  int lin = blockIdx.x + blockIdx.y * gridDim.x;
  int nwg = gridDim.x * GY;  // 640
  int sw = (lin & 7) * (nwg >> 3) + (lin >> 3);
  const int bm = (sw % GY) * 64;
  const int bn = (sw / GY) * 128;

  const short* gsrc[6];
  short* ldst[6];
#pragma unroll
  for (int i = 0; i < 2; ++i) {
    int c = i * 256 + tid;
    int row = c >> 3, slot = c & 7;
    int col = ((slot ^ (row & 7)) << 3);
    gsrc[i] = A + (size_t)(bm + row) * K + col;
    ldst[i] = &As[(i * 256 + (wave << 6)) << 3];
  }
#pragma unroll
  for (int i = 0; i < 4; ++i) {
    int c = i * 256 + tid;
    int row = c >> 3, slot = c & 7;
    int col = ((slot ^ (row & 7)) << 3);
    gsrc[2 + i] = BT + (size_t)(bn + row) * K + col;
    ldst[2 + i] = &Bs[(i * 256 + (wave << 6)) << 3];
  }

  f32x4 acc[2][4] = {};
  const int NT = K >> 6;

  for (int t = 0; t < NT; ++t) {
    if (t) __syncthreads();
#pragma unroll
    for (int i = 0; i < 6; ++i) glds16(gsrc[i] + t * 64, ldst[i]);
    asm volatile("s_waitcnt vmcnt(0)" ::: "memory");
    __syncthreads();
    s16x8 af[2][2], bf[4][2];
#pragma unroll
    for (int m = 0; m < 2; ++m) {
      int rr = wm * 32 + m * 16 + r;
#pragma unroll
      for (int kk = 0; kk < 2; ++kk) {
        int lg = kk * 4 + g;
        af[m][kk] = *(const s16x8*)&As[rr * 64 + ((lg ^ (rr & 7)) << 3)];
      }
    }
#pragma unroll
    for (int n = 0; n < 4; ++n) {
      int rr = wn * 64 + n * 16 + r;
#pragma unroll
      for (int kk = 0; kk < 2; ++kk) {
        int lg = kk * 4 + g;
        bf[n][kk] = *(const s16x8*)&Bs[rr * 64 + ((lg ^ (rr & 7)) << 3)];
      }
    }
#pragma unroll
    for (int m = 0; m < 2; ++m)
#pragma unroll
      for (int n = 0; n < 4; ++n)
#pragma unroll
        for (int kk = 0; kk < 2; ++kk)
          acc[m][n] = __builtin_amdgcn_mfma_f32_16x16x32_bf16(af[m][kk], bf[n][kk], acc[m][n], 0, 0, 0);
  }

  if (bn >= 2304) {
    // V tile 64x128 -> transpose via Bs scratch (8192 shorts exactly)
    __syncthreads();   // all waves done reading Bs (last tile)
    short* ld = &Bs[0];
#pragma unroll
    for (int m = 0; m < 2; ++m) {
      int sl = wm * 32 + m * 16 + g * 4;
#pragma unroll
      for (int n = 0; n < 4; ++n) {
        int dl = wn * 64 + n * 16 + r;
#pragma unroll
        for (int j = 0; j < 4; ++j)
          ld[(sl + j) * 128 + dl] = f2bf(acc[m][n][j]);
      }
    }
    __syncthreads();
    const int dl = tid & 127;
    const int sh = (tid >> 7) * 32;
    short* dst = vt + (size_t)(bn - 2304 + dl) * S_LEN + bm + sh;
#pragma unroll
    for (int v = 0; v < 4; ++v) {
      s16x8 o;
#pragma unroll
      for (int i = 0; i < 8; ++i) o[i] = ld[(sh + v * 8 + i) * 128 + dl];
      *(s16x8*)(dst + v * 8) = o;
    }
  } else {
    // qk-norm over 128 cols of this head (2 wn-waves combine via LDS)
    float ms[2][4], m2[2][4];
#pragma unroll
    for (int m = 0; m < 2; ++m)
#pragma unroll
      for (int j = 0; j < 4; ++j) {
        float s = 0.f, s2 = 0.f;
#pragma unroll
        for (int n = 0; n < 4; ++n) { float v = acc[m][n][j]; s += v; s2 += v * v; }
#pragma unroll
        for (int off = 1; off < 16; off <<= 1) {
          s += __shfl_xor(s, off); s2 += __shfl_xor(s2, off);
        }
        ms[m][j] = s; m2[m][j] = s2;
      }
    if (r == 0) {
#pragma unroll
      for (int m = 0; m < 2; ++m)
#pragma unroll
        for (int j = 0; j < 4; ++j) {
          int rl = wm * 32 + m * 16 + g * 4 + j;
          rsm[wn][rl] = ms[m][j]; rs2m[wn][rl] = m2[m][j];
        }
    }
    __syncthreads();
    const float* gv = (bn < 2048) ? qg : kg;
#pragma unroll
    for (int m = 0; m < 2; ++m)
#pragma unroll
      for (int j = 0; j < 4; ++j) {
        int rl = wm * 32 + m * 16 + g * 4 + j;
        float s = rsm[0][rl] + rsm[1][rl];
        float s2 = rs2m[0][rl] + rs2m[1][rl];
        float mean = s * (1.f / 128.f);
        float var = s2 * (1.f / 128.f) - mean * mean;
        float rstd = rsqrtf(var + LN_EPS);
        int srow = bm + rl;
#pragma unroll
        for (int n = 0; n < 4; ++n) {
          int cl = wn * 64 + n * 16 + r;
          float v = (acc[m][n][j] - mean) * rstd * gv[cl];
          if (bn < 2048) qb[(size_t)srow * 2048 + bn + cl] = f2bf(v);
          else kb[(size_t)srow * 256 + (bn - 2048) + cl] = f2bf(v);
        }
      }
  }
}

// ---------------- Flash attention v3: split K/V waits (proven) -----------
__global__ __launch_bounds__(256)
void attn_fwd3(const short* __restrict__ qbuf, const short* __restrict__ kbuf,
               const short* __restrict__ vtb, short* __restrict__ obuf) {
  __shared__ short Qs[64 * 128];
  __shared__ short Ks[64 * 128];
  __shared__ short Vt[128 * 64];
  __shared__ short Ps[4][16][88];
  const int tid = threadIdx.x;
  int lin = blockIdx.x + blockIdx.y * gridDim.x;
  int sw = (lin & 7) * 32 + (lin >> 3);
  const int pair = sw & 15;
  const int h = sw >> 4;
  const int kh = h >> 3;
  const int wave = tid >> 6, lane = tid & 63;
  const int g = lane >> 4, r = lane & 15;
  const float scale = 0.08838834764831845f;

#pragma unroll
  for (int half = 0; half < 2; ++half) {
    const int qt = half ? (31 - pair) : pair;
    const int qbase = qt * 64;
    __builtin_amdgcn_s_barrier();
#pragma unroll
    for (int i = 0; i < 4; ++i) {
      int c = i * 256 + tid;
      int row = c >> 4;
      int scol = (((c & 15) ^ (row & 7)) << 3);
      glds16(qbuf + (size_t)(qbase + row) * DMODEL + h * DHEAD + scol,
             &Qs[(i * 256 + (wave << 6)) << 3]);
    }
    f32x4 O[8] = {};
    float mst[4], lst[4];
#pragma unroll
    for (int j = 0; j < 4; ++j) { mst[j] = -1e30f; lst[j] = 0.f; }
    s16x8 aq[4];

    for (int jt = 0; jt <= qt; ++jt) {
      const int jb = jt * 64;
      if (jt) __builtin_amdgcn_s_barrier();
#pragma unroll
      for (int i = 0; i < 4; ++i) {
        int c = i * 256 + tid;
        int row = c >> 4;
        int scol = (((c & 15) ^ (row & 7)) << 3);
        glds16(kbuf + (size_t)(jb + row) * 256 + kh * DHEAD + scol,
               &Ks[(i * 256 + (wave << 6)) << 3]);
      }
#pragma unroll
      for (int i = 0; i < 4; ++i) {
        int c = i * 256 + tid;
        int row = c >> 3;
        int scol = (((c & 7) ^ (row & 7)) << 3);
        glds16(vtb + (size_t)(kh * 128 + row) * S_LEN + jb + scol,
               &Vt[(i * 256 + (wave << 6)) << 3]);
      }
      asm volatile("s_waitcnt vmcnt(4)" ::: "memory");
      __builtin_amdgcn_s_barrier();
      if (jt == 0) {
#pragma unroll
        for (int kc = 0; kc < 4; ++kc) {
          int rr = wave * 16 + r;
          aq[kc] = *(const s16x8*)&Qs[rr * 128 + ((((kc << 2) | g) ^ (rr & 7)) << 3)];
        }
      }
      f32x4 sc[4] = {};
      __builtin_amdgcn_s_setprio(1);
#pragma unroll
      for (int n = 0; n < 4; ++n) {
        int rr = n * 16 + r;
#pragma unroll
        for (int kc = 0; kc < 4; ++kc) {
          s16x8 bk = *(const s16x8*)&Ks[rr * 128 + ((((kc << 2) | g) ^ (rr & 7)) << 3)];
          sc[n] = __builtin_amdgcn_mfma_f32_16x16x32_bf16(aq[kc], bk, sc[n], 0, 0, 0);
        }
      }
      __builtin_amdgcn_s_setprio(0);
      if (jt == qt) {
#pragma unroll
        for (int j = 0; j < 4; ++j) {
          int irow = qbase + wave * 16 + g * 4 + j;
#pragma unroll
          for (int n = 0; n < 4; ++n) {
            int jcol = jb + n * 16 + r;
            sc[n][j] = (jcol <= irow) ? sc[n][j] * scale : -1e30f;
          }
        }
      } else {
#pragma unroll
        for (int j = 0; j < 4; ++j)
#pragma unroll
          for (int n = 0; n < 4; ++n) sc[n][j] *= scale;
      }
      float pmax[4], alpha[4], rsum[4];
#pragma unroll
      for (int j = 0; j < 4; ++j)
        pmax[j] = fmaxf(fmaxf(sc[0][j], sc[1][j]), fmaxf(sc[2][j], sc[3][j]));
#pragma unroll
      for (int off = 1; off < 16; off <<= 1)
#pragma unroll
        for (int j = 0; j < 4; ++j) pmax[j] = fmaxf(pmax[j], __shfl_xor(pmax[j], off));
#pragma unroll
      for (int j = 0; j < 4; ++j) {
        float mnew = fmaxf(mst[j], pmax[j]);
        alpha[j] = __expf(mst[j] - mnew);
        mst[j] = mnew;
#pragma unroll
        for (int n = 0; n < 4; ++n) sc[n][j] = __expf(sc[n][j] - mnew);
        rsum[j] = (sc[0][j] + sc[1][j]) + (sc[2][j] + sc[3][j]);
      }
#pragma unroll
      for (int off = 1; off < 16; off <<= 1)
#pragma unroll
        for (int j = 0; j < 4; ++j) rsum[j] += __shfl_xor(rsum[j], off);
#pragma unroll
      for (int j = 0; j < 4; ++j) lst[j] = lst[j] * alpha[j] + rsum[j];
#pragma unroll
      for (int d = 0; d < 8; ++d)
#pragma unroll
        for (int j = 0; j < 4; ++j) O[d][j] *= alpha[j];
      asm volatile("s_waitcnt vmcnt(0)" ::: "memory");
      __builtin_amdgcn_s_barrier();
#pragma unroll
      for (int j = 0; j < 4; ++j)
#pragma unroll
        for (int n = 0; n < 4; ++n)
          Ps[wave][g * 4 + j][n * 16 + r] = f2bf(sc[n][j]);
      s16x8 pa0 = *(const s16x8*)&Ps[wave][r][g * 8];
      s16x8 pa1 = *(const s16x8*)&Ps[wave][r][32 + g * 8];
      __builtin_amdgcn_s_setprio(1);
#pragma unroll
      for (int d = 0; d < 8; ++d) {
        int dd = d * 16 + r;
        s16x8 b0 = *(const s16x8*)&Vt[dd * 64 + ((g ^ (dd & 7)) << 3)];
        s16x8 b1 = *(const s16x8*)&Vt[dd * 64 + (((4 + g) ^ (dd & 7)) << 3)];
        O[d] = __builtin_amdgcn_mfma_f32_16x16x32_bf16(pa0, b0, O[d], 0, 0, 0);
        O[d] = __builtin_amdgcn_mfma_f32_16x16x32_bf16(pa1, b1, O[d], 0, 0, 0);
      }
      __builtin_amdgcn_s_setprio(0);
    }
    float linv[4];
#pragma unroll
    for (int j = 0; j < 4; ++j) linv[j] = 1.f / lst[j];
#pragma unroll
    for (int d = 0; d < 8; ++d)
#pragma unroll
      for (int j = 0; j < 4; ++j)
        obuf[(size_t)(qbase + wave * 16 + g * 4 + j) * DMODEL + h * DHEAD + d * 16 + r] =
            f2bf(O[d][j] * linv[j]);
  }
}

// ---------------- host side ----------------
extern "C" void kernel_launch(void* const* d_in, const int* in_sizes, int n_in,
                              void* d_out, int out_size, void* d_ws, size_t ws_size,
                              hipStream_t stream) {
  const int* text = (const int*)d_in[0];
  const float* embed_w = (const float*)d_in[1];
  const float* model_g = (const float*)d_in[2];
  const float* model_b = (const float*)d_in[3];
  const float* blk_g = (const float*)d_in[4];
  const float* blk_b = (const float*)d_in[5];
  const float* attn_g = (const float*)d_in[6];
  const float* attn_b = (const float*)d_in[7];
  const float* wq = (const float*)d_in[8];
  const float* wk = (const float*)d_in[9];
  const float* wv = (const float*)d_in[10];
  const float* wo = (const float*)d_in[11];
  const float* qn_g = (const float*)d_in[12];
  const float* kn_g = (const float*)d_in[13];
  const float* w1 = (const float*)d_in[14];
  const float* b1 = (const float*)d_in[15];
  const float* w2 = (const float*)d_in[16];
  const float* b2 = (const float*)d_in[17];
  const float* head_g = (const float*)d_in[18];
  const float* head_b = (const float*)d_in[19];
  const float* head_w = (const float*)d_in[20];
  const float* head_bias = (const float*)d_in[21];
  float* out = (float*)d_out;

  const size_t SD = (size_t)S_LEN * DMODEL;
  const size_t SKV = (size_t)S_LEN * KVHEAD * DHEAD;
  const size_t SI = (size_t)S_LEN * INNER_DIM;
  const size_t WD = (size_t)DMODEL * DMODEL;
  const size_t WKV = (size_t)DMODEL * KVHEAD * DHEAD;
  const size_t WI = (size_t)DMODEL * INNER_DIM;

  char* p = (char*)d_ws;
  float* wpart = (float*)p; p += SD * 4 * 2;
  short* hb16  = (short*)p; p += SD * 2;
  short* hn16  = (short*)p; p += SD * 2;
  short* h216  = (short*)p; p += SD * 2;
  short* ao16  = (short*)p; p += SD * 2;
  short* ffi16 = (short*)p; p += SI * 2;
  short* qb16  = (short*)p; p += SD * 2;
  short* kb16  = (short*)p; p += SKV * 2;
  short* vt16  = (short*)p; p += SKV * 2;
  short* wqkvT = (short*)p; p += (size_t)QKVN * DMODEL * 2;
  short* woT   = (short*)p; p += WD * 2;
  short* w1T   = (short*)p; p += WI * 2;
  short* w2T   = (short*)p; p += WI * 2;
  short* headT = w1T;

  dim3 blk(256);
  embed_ln3<<<S_LEN, blk, 0, stream>>>(text, embed_w, model_g, model_b,
                                       blk_g, blk_b, attn_g, attn_b, hb16, hn16);

  for (int i = 0; i < NLAYER; ++i) {
    wtrans_all<<<10496, blk, 0, stream>>>(
        wq + (size_t)i * WD, wk + (size_t)i * WKV, wv + (size_t)i * WKV,
        wo + (size_t)i * WD, w1 + (size_t)i * WI, w2 + (size_t)i * WI,
        wqkvT, woT, w1T, w2T);

    // qkv: single-buffered 64x128 -> 640 blocks
    gemm_qkv<<<dim3(QKVN / 128, S_LEN / 64), blk, 0, stream>>>(
        hn16, wqkvT, qn_g + i * DHEAD, kn_g + i * DHEAD,
        qb16, kb16, vt16, S_LEN, DMODEL);

    attn_fwd3<<<dim3(16, 16), blk, 0, stream>>>(qb16, kb16, vt16, ao16);

    // h2(bf16) = ao @ wo + hb16 : single-buffered 64x128 -> 512 blocks
    gemm_sb<64, 128, 64, 2, 2, 0, false, true, false, true, false>
        <<<dim3(DMODEL / 128, S_LEN / 64), blk, 0, stream>>>(
        ao16, woT, nullptr, hb16, nullptr, h216,
        S_LEN, DMODEL, DMODEL, DMODEL, DMODEL);
    // ffi = gelu(h2 @ w1 + b1): single-buffered 128^2 -> 1024 blocks
    gemm_sb<128, 128, 64, 2, 2, 1, true, false, false, true, false>
        <<<dim3(INNER_DIM / 128, S_LEN / 128), blk, 0, stream>>>(
        h216, w1T, b1 + (size_t)i * INNER_DIM, nullptr, nullptr, ffi16,
        S_LEN, INNER_DIM, DMODEL, DMODEL, DMODEL);
    // w2: split-K x2, single-buffered -> 512 blocks
    gemm_sb<128, 128, 64, 2, 2, 0, false, false, true, false, true>
        <<<dim3(DMODEL / 128, S_LEN / 128, 2), blk, 0, stream>>>(
        ffi16, w2T, nullptr, nullptr, wpart, nullptr,
        S_LEN, DMODEL, INNER_DIM / 2, INNER_DIM, INNER_DIM);

    if (i + 1 < NLAYER) {
      ln_triple_sum<<<S_LEN, blk, 0, stream>>>(
          wpart, wpart + SD, h216, b2 + (size_t)i * DMODEL,
          model_g, model_b,
          blk_g + (i + 1) * DMODEL, blk_b + (i + 1) * DMODEL,
          attn_g + (i + 1) * DMODEL, attn_b + (i + 1) * DMODEL, hb16, hn16);
    } else {
      ln_dual_sum<<<S_LEN, blk, 0, stream>>>(
          wpart, wpart + SD, h216, b2 + (size_t)i * DMODEL,
          model_g, model_b, head_g, head_b, hn16);
    }
  }

  wtrans64<<<dim3(VOCAB_PAD / 64, 32), blk, 0, stream>>>(head_w, headT, DMODEL, VOCAB, VOCAB_PAD);
  // head: single-buffered 128^2 -> 1280 blocks
  gemm_sb<128, 128, 64, 2, 2, 0, true, false, true, false, false>
      <<<dim3(VOCAB_PAD / 128, S_LEN / 128), blk, 0, stream>>>(
      hn16, headT, head_bias, nullptr, out, nullptr,
      S_LEN, VOCAB, DMODEL, DMODEL, DMODEL);
}

// Round 16
// 1473.341 us; speedup vs baseline: 1.0335x; 1.0335x over previous
//
#include <hip/hip_runtime.h>
#include <math.h>

#define S_LEN 2048
#define DMODEL 2048
#define NHEAD 16
#define KVHEAD 2
#define DHEAD 128
#define NLAYER 4
#define VOCAB 10000
#define INNER_DIM 8192
#define LN_EPS 1e-5f
#define VOCAB_PAD 10240
#define QKVN 2560

typedef __attribute__((ext_vector_type(4))) float f32x4;
typedef __attribute__((ext_vector_type(2))) float f32x2;
typedef __attribute__((ext_vector_type(8))) short s16x8;
typedef __attribute__((ext_vector_type(4))) short s16x4;

__device__ __forceinline__ short f2bf(float f) {
  union { float f; unsigned u; } v; v.f = f;
  unsigned r = v.u + 0x7FFFu + ((v.u >> 16) & 1u);  // RNE
  return (short)(r >> 16);
}
__device__ __forceinline__ float bf2f(short s) {
  union { unsigned u; float f; } v; v.u = ((unsigned)(unsigned short)s) << 16;
  return v.f;
}

__device__ __forceinline__ float gelu_tanh(float x) {
  float z = 0.7978845608028654f * (x + 0.044715f * x * x * x);
  float t = __expf(-2.0f * fabsf(z));
  float th = (1.0f - t) / (1.0f + t);
  th = copysignf(th, z);
  return 0.5f * x * (1.0f + th);
}

__device__ __forceinline__ void glds16(const void* g, void* l) {
  __builtin_amdgcn_global_load_lds(
      (const __attribute__((address_space(1))) unsigned int*)g,
      (__attribute__((address_space(3))) unsigned int*)l, 16, 0, 0);
}

// ---------------- ALL per-layer weight transposes in one launch ----------
__global__ __launch_bounds__(256)
void wtrans_all(const float* __restrict__ wq, const float* __restrict__ wk,
                const float* __restrict__ wv, const float* __restrict__ wo,
                const float* __restrict__ w1, const float* __restrict__ w2,
                short* __restrict__ wqkvT, short* __restrict__ woT,
                short* __restrict__ w1T, short* __restrict__ w2T) {
  __shared__ float ld[64][65];
  int b = blockIdx.x;
  const float* W; short* WT; int gx, K;
  if (b < 1024)      { W = wq; WT = wqkvT; gx = 32; K = 2048; }
  else if (b < 1152) { b -= 1024; W = wk; WT = wqkvT + (size_t)2048 * 2048; gx = 4; K = 2048; }
  else if (b < 1280) { b -= 1152; W = wv; WT = wqkvT + (size_t)2304 * 2048; gx = 4; K = 2048; }
  else if (b < 2304) { b -= 1280; W = wo; WT = woT; gx = 32; K = 2048; }
  else if (b < 6400) { b -= 2304; W = w1; WT = w1T; gx = 128; K = 2048; }
  else               { b -= 6400; W = w2; WT = w2T; gx = 32; K = 8192; }
  const int N = gx * 64;
  const int n0 = (b % gx) * 64, k0 = (b / gx) * 64;
  const int tid = threadIdx.x;
  const int rbase = tid >> 4;
  const int c4 = (tid & 15) * 4;
#pragma unroll
  for (int q = 0; q < 4; ++q) {
    int kk = rbase + q * 16;
    f32x4 v = *(const f32x4*)(W + (size_t)(k0 + kk) * N + n0 + c4);
    ld[kk][c4 + 0] = v[0]; ld[kk][c4 + 1] = v[1];
    ld[kk][c4 + 2] = v[2]; ld[kk][c4 + 3] = v[3];
  }
  __syncthreads();
#pragma unroll
  for (int s = 0; s < 2; ++s) {
    int lin = tid + s * 256;
    int nn = lin >> 3;
    int ks = lin & 7;
    s16x8 o;
#pragma unroll
    for (int j = 0; j < 8; ++j) o[j] = f2bf(ld[ks * 8 + j][nn]);
    *(s16x8*)&WT[(size_t)(n0 + nn) * K + k0 + ks * 8] = o;
  }
}

// ---------------- head weight transpose (edge at N=10000) ----------------
__global__ __launch_bounds__(256)
void wtrans64(const float* __restrict__ W, short* __restrict__ WT,
              int K, int N, int NP) {
  __shared__ float ld[64][65];
  const int n0 = blockIdx.x * 64, k0 = blockIdx.y * 64;
  const int tid = threadIdx.x;
  const int rbase = tid >> 4;
  const int c4 = (tid & 15) * 4;
#pragma unroll
  for (int q = 0; q < 4; ++q) {
    int kk = rbase + q * 16;
    const float* wp = W + (size_t)(k0 + kk) * N + n0 + c4;
    float v0, v1, v2, v3;
    if (n0 + c4 + 3 < N) {
      f32x4 v = *(const f32x4*)wp;
      v0 = v[0]; v1 = v[1]; v2 = v[2]; v3 = v[3];
    } else {
      v0 = (n0 + c4 + 0 < N) ? wp[0] : 0.f;
      v1 = (n0 + c4 + 1 < N) ? wp[1] : 0.f;
      v2 = (n0 + c4 + 2 < N) ? wp[2] : 0.f;
      v3 = (n0 + c4 + 3 < N) ? wp[3] : 0.f;
    }
    ld[kk][c4 + 0] = v0; ld[kk][c4 + 1] = v1;
    ld[kk][c4 + 2] = v2; ld[kk][c4 + 3] = v3;
  }
  __syncthreads();
#pragma unroll
  for (int s = 0; s < 2; ++s) {
    int lin = tid + s * 256;
    int nn = lin >> 3;
    int ks = lin & 7;
    int n = n0 + nn;
    if (n < NP) {
      s16x8 o;
#pragma unroll
      for (int j = 0; j < 8; ++j)
        o[j] = (n < N) ? f2bf(ld[ks * 8 + j][nn]) : (short)0;
      *(s16x8*)&WT[(size_t)n * K + k0 + ks * 8] = o;
    }
  }
}

// ---------------- LN core: 3 rounds (hb bf16) ----------------
__device__ __forceinline__ void ln3_core(
    float (&v)[8], int tid, int wave,
    const float* __restrict__ mg, const float* __restrict__ mb,
    const float* __restrict__ bg, const float* __restrict__ bb,
    const float* __restrict__ ag, const float* __restrict__ ab,
    short* __restrict__ hbrow, short* __restrict__ hnrow,
    float rs[3][4], float rs2[3][4]) {
#pragma unroll
  for (int rnd = 0; rnd < 3; ++rnd) {
    float s = 0.f, s2 = 0.f;
#pragma unroll
    for (int i = 0; i < 8; ++i) { s += v[i]; s2 += v[i] * v[i]; }
#pragma unroll
    for (int off = 1; off < 64; off <<= 1) {
      s += __shfl_xor(s, off); s2 += __shfl_xor(s2, off);
    }
    if ((tid & 63) == 0) { rs[rnd][wave] = s; rs2[rnd][wave] = s2; }
    __syncthreads();
    s = rs[rnd][0] + rs[rnd][1] + rs[rnd][2] + rs[rnd][3];
    s2 = rs2[rnd][0] + rs2[rnd][1] + rs2[rnd][2] + rs2[rnd][3];
    const float mean = s * (1.f / DMODEL);
    const float var = s2 * (1.f / DMODEL) - mean * mean;
    const float rstd = rsqrtf(var + LN_EPS);
    const float* gg = (rnd == 0) ? mg : (rnd == 1) ? bg : ag;
    const float* bbv = (rnd == 0) ? mb : (rnd == 1) ? bb : ab;
#pragma unroll
    for (int i = 0; i < 8; ++i) {
      int idx = tid + i * 256;
      v[i] = (v[i] - mean) * rstd * gg[idx] + bbv[idx];
    }
    if (rnd == 1) {
#pragma unroll
      for (int i = 0; i < 8; ++i) hbrow[tid + i * 256] = f2bf(v[i]);
    }
  }
#pragma unroll
  for (int i = 0; i < 8; ++i) hnrow[tid + i * 256] = f2bf(v[i]);
}

__global__ __launch_bounds__(256)
void embed_ln3(const int* __restrict__ text, const float* __restrict__ ew,
               const float* __restrict__ mg, const float* __restrict__ mb,
               const float* __restrict__ bg, const float* __restrict__ bb,
               const float* __restrict__ ag, const float* __restrict__ ab,
               short* __restrict__ hb16, short* __restrict__ hn16) {
  const int row = blockIdx.x;
  const int tid = threadIdx.x;
  const int wave = tid >> 6;
  __shared__ float rs[3][4], rs2[3][4];
  float v[8];
  const float* x = ew + (size_t)text[row] * DMODEL;
#pragma unroll
  for (int i = 0; i < 8; ++i) v[i] = x[tid + i * 256];
  ln3_core(v, tid, wave, mg, mb, bg, bb, ag, ab,
           hb16 + (size_t)row * DMODEL, hn16 + (size_t)row * DMODEL, rs, rs2);
}

__global__ __launch_bounds__(256)
void ln_triple_sum(const float* __restrict__ p0, const float* __restrict__ p1,
                   const short* __restrict__ h216, const float* __restrict__ b2,
                   const float* __restrict__ mg, const float* __restrict__ mb,
                   const float* __restrict__ bg, const float* __restrict__ bb,
                   const float* __restrict__ ag, const float* __restrict__ ab,
                   short* __restrict__ hb16, short* __restrict__ hn16) {
  const int row = blockIdx.x;
  const int tid = threadIdx.x;
  const int wave = tid >> 6;
  __shared__ float rs[3][4], rs2[3][4];
  float v[8];
  const size_t base = (size_t)row * DMODEL;
#pragma unroll
  for (int i = 0; i < 8; ++i) {
    int idx = tid + i * 256;
    v[i] = p0[base + idx] + p1[base + idx] + b2[idx] + bf2f(h216[base + idx]);
  }
  ln3_core(v, tid, wave, mg, mb, bg, bb, ag, ab,
           hb16 + base, hn16 + base, rs, rs2);
}

__global__ __launch_bounds__(256)
void ln_dual_sum(const float* __restrict__ p0, const float* __restrict__ p1,
                 const short* __restrict__ h216, const float* __restrict__ b2,
                 const float* __restrict__ mg, const float* __restrict__ mb,
                 const float* __restrict__ hg, const float* __restrict__ hbv,
                 short* __restrict__ out16) {
  const int row = blockIdx.x;
  const int tid = threadIdx.x;
  const int wave = tid >> 6;
  __shared__ float rs[2][4], rs2[2][4];
  float v[8];
  const size_t base = (size_t)row * DMODEL;
#pragma unroll
  for (int i = 0; i < 8; ++i) {
    int idx = tid + i * 256;
    v[i] = p0[base + idx] + p1[base + idx] + b2[idx] + bf2f(h216[base + idx]);
  }
#pragma unroll
  for (int rnd = 0; rnd < 2; ++rnd) {
    float s = 0.f, s2 = 0.f;
#pragma unroll
    for (int i = 0; i < 8; ++i) { s += v[i]; s2 += v[i] * v[i]; }
#pragma unroll
    for (int off = 1; off < 64; off <<= 1) {
      s += __shfl_xor(s, off); s2 += __shfl_xor(s2, off);
    }
    if ((tid & 63) == 0) { rs[rnd][wave] = s; rs2[rnd][wave] = s2; }
    __syncthreads();
    s = rs[rnd][0] + rs[rnd][1] + rs[rnd][2] + rs[rnd][3];
    s2 = rs2[rnd][0] + rs2[rnd][1] + rs2[rnd][2] + rs2[rnd][3];
    const float mean = s * (1.f / DMODEL);
    const float var = s2 * (1.f / DMODEL) - mean * mean;
    const float rstd = rsqrtf(var + LN_EPS);
    const float* gg = (rnd == 0) ? mg : hg;
    const float* bbv = (rnd == 0) ? mb : hbv;
#pragma unroll
    for (int i = 0; i < 8; ++i) {
      int idx = tid + i * 256;
      v[i] = (v[i] - mean) * rstd * gg[idx] + bbv[idx];
    }
  }
  short* o = out16 + base;
#pragma unroll
  for (int i = 0; i < 8; ++i) o[tid + i * 256] = f2bf(v[i]);
}

// ---------------- 2-phase double-buffered bf16 GEMM -----------------------
// BM may differ from BN; optional split-K via blockIdx.z; residual may be
// bf16 (RESB) or absent.
template<int BM, int BN, int BK, int WM, int WN, int ACT, bool BIAS, bool RESB,
         bool WF, bool WB, bool SPLITK>
__global__ __launch_bounds__(WM * WN * 64)
void gemm_db(const short* __restrict__ A, const short* __restrict__ BT,
             const float* __restrict__ bias, const short* __restrict__ res16,
             float* __restrict__ Cf, short* __restrict__ Cb,
             int M, int N, int K, int LDA, int LDB) {
  constexpr int THREADS = WM * WN * 64;
  constexpr int MR = BM / WM / 16;
  constexpr int NR = BN / WN / 16;
  constexpr int KH = BK / 32;
  constexpr int SLOTS = BK / 8;
  constexpr int SMASK = SLOTS - 1;
  constexpr int RSH = (SLOTS == 8) ? 0 : 1;
  constexpr int CSH = (SLOTS == 8) ? 3 : 2;
  constexpr int NIA = (BM * BK) / (THREADS * 8);
  constexpr int NIB = (BN * BK) / (THREADS * 8);
  __shared__ short As[2][BM * BK];
  __shared__ short Bs[2][BN * BK];
  const int tid = threadIdx.x;
  const int wave = tid >> 6, lane = tid & 63;
  const int g = lane >> 4, r = lane & 15;
  const int wm = wave / WN, wn = wave % WN;
  const int zoff = SPLITK ? blockIdx.z * K : 0;
  if (SPLITK && WF) Cf += (size_t)blockIdx.z * M * N;

  const int GY = gridDim.y;
  int lin = blockIdx.x + blockIdx.y * gridDim.x;
  int nwg = gridDim.x * GY;
  int sw = ((nwg & 7) == 0) ? ((lin & 7) * (nwg >> 3) + (lin >> 3)) : lin;
  const int bm = (sw % GY) * BM;
  const int bn = (sw / GY) * BN;

  const short* gsrc[NIA + NIB];
  short* ldst[2][NIA + NIB];
#pragma unroll
  for (int i = 0; i < NIA; ++i) {
    int c = i * THREADS + tid;
    int row = c >> CSH;
    int slot = c & SMASK;
    int col = ((slot ^ ((row >> RSH) & SMASK)) << 3);
    gsrc[i] = A + (size_t)(bm + row) * LDA + zoff + col;
    int base = (i * THREADS + (wave << 6)) << 3;
    ldst[0][i] = &As[0][base];
    ldst[1][i] = &As[1][base];
  }
#pragma unroll
  for (int i = 0; i < NIB; ++i) {
    int c = i * THREADS + tid;
    int row = c >> CSH;
    int slot = c & SMASK;
    int col = ((slot ^ ((row >> RSH) & SMASK)) << 3);
    gsrc[NIA + i] = BT + (size_t)(bn + row) * LDB + zoff + col;
    int base = (i * THREADS + (wave << 6)) << 3;
    ldst[0][NIA + i] = &Bs[0][base];
    ldst[1][NIA + i] = &Bs[1][base];
  }

  f32x4 acc[MR][NR] = {};
  const int NT = K / BK;

#pragma unroll
  for (int i = 0; i < NIA + NIB; ++i) glds16(gsrc[i], ldst[0][i]);
  asm volatile("s_waitcnt vmcnt(0)" ::: "memory");
  __syncthreads();

  for (int t = 0; t < NT; ++t) {
    const int cur = t & 1;
    const short* as = As[cur];
    const short* bs = Bs[cur];
    s16x8 bfr[NR][KH], af[(MR > 1) ? MR / 2 : 1][KH];
#pragma unroll
    for (int n = 0; n < NR; ++n) {
      int rr = wn * (NR * 16) + n * 16 + r;
#pragma unroll
      for (int kk = 0; kk < KH; ++kk) {
        int lg = kk * 4 + g;
        bfr[n][kk] = *(const s16x8*)&bs[rr * BK + ((lg ^ ((rr >> RSH) & SMASK)) << 3)];
      }
    }
#pragma unroll
    for (int mm = 0; mm < MR / 2; ++mm) {
      int rr = wm * (MR * 16) + mm * 16 + r;
#pragma unroll
      for (int kk = 0; kk < KH; ++kk) {
        int lg = kk * 4 + g;
        af[mm][kk] = *(const s16x8*)&as[rr * BK + ((lg ^ ((rr >> RSH) & SMASK)) << 3)];
      }
    }
    if (t + 1 < NT) {
#pragma unroll
      for (int i = 0; i < NIA + NIB; ++i) glds16(gsrc[i] + (t + 1) * BK, ldst[cur ^ 1][i]);
    }
    asm volatile("s_waitcnt lgkmcnt(0)" ::: "memory");
    __builtin_amdgcn_sched_barrier(0);
    __builtin_amdgcn_s_setprio(1);
#pragma unroll
    for (int mm = 0; mm < MR / 2; ++mm)
#pragma unroll
      for (int n = 0; n < NR; ++n)
#pragma unroll
        for (int kk = 0; kk < KH; ++kk)
          acc[mm][n] = __builtin_amdgcn_mfma_f32_16x16x32_bf16(af[mm][kk], bfr[n][kk], acc[mm][n], 0, 0, 0);
    __builtin_amdgcn_s_setprio(0);
    __builtin_amdgcn_s_barrier();
#pragma unroll
    for (int mm = 0; mm < MR / 2; ++mm) {
      int rr = wm * (MR * 16) + (MR / 2 + mm) * 16 + r;
#pragma unroll
      for (int kk = 0; kk < KH; ++kk) {
        int lg = kk * 4 + g;
        af[mm][kk] = *(const s16x8*)&as[rr * BK + ((lg ^ ((rr >> RSH) & SMASK)) << 3)];
      }
    }
    asm volatile("s_waitcnt lgkmcnt(0)" ::: "memory");
    __builtin_amdgcn_sched_barrier(0);
    __builtin_amdgcn_s_setprio(1);
#pragma unroll
    for (int mm = 0; mm < MR / 2; ++mm)
#pragma unroll
      for (int n = 0; n < NR; ++n)
#pragma unroll
        for (int kk = 0; kk < KH; ++kk)
          acc[MR / 2 + mm][n] = __builtin_amdgcn_mfma_f32_16x16x32_bf16(af[mm][kk], bfr[n][kk], acc[MR / 2 + mm][n], 0, 0, 0);
    __builtin_amdgcn_s_setprio(0);
    __syncthreads();
  }

#pragma unroll
  for (int m = 0; m < MR; ++m) {
    int row = bm + wm * (MR * 16) + m * 16 + g * 4;
#pragma unroll
    for (int n = 0; n < NR; ++n) {
      int col = bn + wn * (NR * 16) + n * 16 + r;
      if (col < N) {
#pragma unroll
        for (int j = 0; j < 4; ++j) {
          float v = acc[m][n][j];
          if (BIAS) v += bias[col];
          if (ACT) v = gelu_tanh(v);
          if (RESB) v += bf2f(res16[(size_t)(row + j) * N + col]);
          if (WF) Cf[(size_t)(row + j) * N + col] = v;
          if (WB) Cb[(size_t)(row + j) * N + col] = f2bf(v);
        }
      }
    }
  }
}

// ---------------- qkv GEMM: 64x128 tiles, fused qk-norm + V-transpose ----
// grid (20,32) = 640 blocks (2-3 resident/CU). Each col-tile is one head.
__global__ __launch_bounds__(256)
void gemm_qkv(const short* __restrict__ A, const short* __restrict__ BT,
              const float* __restrict__ qg, const float* __restrict__ kg,
              short* __restrict__ qb, short* __restrict__ kb,
              short* __restrict__ vt, int M, int K) {
  __shared__ short As[2][64 * 64];    // A tile 64x64(k)
  __shared__ short Bs[2][128 * 64];   // B tile 128x64(k)
  __shared__ float rsm[2][64], rs2m[2][64];
  const int tid = threadIdx.x;
  const int wave = tid >> 6, lane = tid & 63;
  const int g = lane >> 4, r = lane & 15;
  const int wm = wave >> 1, wn = wave & 1;   // 2x2 waves: 32-row x 64-col each

  const int GY = gridDim.y;  // 32
  int lin = blockIdx.x + blockIdx.y * gridDim.x;
  int nwg = gridDim.x * GY;  // 640 % 8 == 0
  int sw = (lin & 7) * (nwg >> 3) + (lin >> 3);
  const int bm = (sw % GY) * 64;
  const int bn = (sw / GY) * 128;

  const short* gsrc[6];
  short* ldst[2][6];
#pragma unroll
  for (int i = 0; i < 2; ++i) {   // A: 512 chunks / 256 thr = 2
    int c = i * 256 + tid;
    int row = c >> 3, slot = c & 7;
    int col = ((slot ^ (row & 7)) << 3);
    gsrc[i] = A + (size_t)(bm + row) * K + col;
    int base = (i * 256 + (wave << 6)) << 3;
    ldst[0][i] = &As[0][base];
    ldst[1][i] = &As[1][base];
  }
#pragma unroll
  for (int i = 0; i < 4; ++i) {   // B: 1024 chunks / 256 thr = 4
    int c = i * 256 + tid;
    int row = c >> 3, slot = c & 7;
    int col = ((slot ^ (row & 7)) << 3);
    gsrc[2 + i] = BT + (size_t)(bn + row) * K + col;
    int base = (i * 256 + (wave << 6)) << 3;
    ldst[0][2 + i] = &Bs[0][base];
    ldst[1][2 + i] = &Bs[1][base];
  }

  f32x4 acc[2][4] = {};
  const int NT = K >> 6;

#pragma unroll
  for (int i = 0; i < 6; ++i) glds16(gsrc[i], ldst[0][i]);
  asm volatile("s_waitcnt vmcnt(0)" ::: "memory");
  __syncthreads();

  for (int t = 0; t < NT; ++t) {
    const int cur = t & 1;
    const short* as = As[cur];
    const short* bs = Bs[cur];
    s16x8 bfr[4][2], af[1][2];
#pragma unroll
    for (int n = 0; n < 4; ++n) {
      int rr = wn * 64 + n * 16 + r;
#pragma unroll
      for (int kk = 0; kk < 2; ++kk) {
        int lg = kk * 4 + g;
        bfr[n][kk] = *(const s16x8*)&bs[rr * 64 + ((lg ^ (rr & 7)) << 3)];
      }
    }
    {
      int rr = wm * 32 + r;
#pragma unroll
      for (int kk = 0; kk < 2; ++kk) {
        int lg = kk * 4 + g;
        af[0][kk] = *(const s16x8*)&as[rr * 64 + ((lg ^ (rr & 7)) << 3)];
      }
    }
    if (t + 1 < NT) {
#pragma unroll
      for (int i = 0; i < 6; ++i) glds16(gsrc[i] + (t + 1) * 64, ldst[cur ^ 1][i]);
    }
    asm volatile("s_waitcnt lgkmcnt(0)" ::: "memory");
    __builtin_amdgcn_sched_barrier(0);
    __builtin_amdgcn_s_setprio(1);
#pragma unroll
    for (int n = 0; n < 4; ++n)
#pragma unroll
      for (int kk = 0; kk < 2; ++kk)
        acc[0][n] = __builtin_amdgcn_mfma_f32_16x16x32_bf16(af[0][kk], bfr[n][kk], acc[0][n], 0, 0, 0);
    __builtin_amdgcn_s_setprio(0);
    __builtin_amdgcn_s_barrier();
    {
      int rr = wm * 32 + 16 + r;
#pragma unroll
      for (int kk = 0; kk < 2; ++kk) {
        int lg = kk * 4 + g;
        af[0][kk] = *(const s16x8*)&as[rr * 64 + ((lg ^ (rr & 7)) << 3)];
      }
    }
    asm volatile("s_waitcnt lgkmcnt(0)" ::: "memory");
    __builtin_amdgcn_sched_barrier(0);
    __builtin_amdgcn_s_setprio(1);
#pragma unroll
    for (int n = 0; n < 4; ++n)
#pragma unroll
      for (int kk = 0; kk < 2; ++kk)
        acc[1][n] = __builtin_amdgcn_mfma_f32_16x16x32_bf16(af[0][kk], bfr[n][kk], acc[1][n], 0, 0, 0);
    __builtin_amdgcn_s_setprio(0);
    __syncthreads();
  }

  if (bn >= 2304) {
    // V tile 64x128: LDS transpose via As (2*4096 = 8192 shorts = 64*128)
    short* ld = &As[0][0];
#pragma unroll
    for (int m = 0; m < 2; ++m) {
      int sl = wm * 32 + m * 16 + g * 4;
#pragma unroll
      for (int n = 0; n < 4; ++n) {
        int dl = wn * 64 + n * 16 + r;
#pragma unroll
        for (int j = 0; j < 4; ++j)
          ld[(sl + j) * 128 + dl] = f2bf(acc[m][n][j]);
      }
    }
    __syncthreads();
    const int dl = tid & 127;
    const int sh = (tid >> 7) * 32;
    short* dst = vt + (size_t)(bn - 2304 + dl) * S_LEN + bm + sh;
#pragma unroll
    for (int v = 0; v < 4; ++v) {
      s16x8 o;
#pragma unroll
      for (int i = 0; i < 8; ++i) o[i] = ld[(sh + v * 8 + i) * 128 + dl];
      *(s16x8*)(dst + v * 8) = o;
    }
  } else {
    // qk-norm over 128 cols of this head (2 wn-waves combine via LDS)
    float ms[2][4], m2[2][4];
#pragma unroll
    for (int m = 0; m < 2; ++m)
#pragma unroll
      for (int j = 0; j < 4; ++j) {
        float s = 0.f, s2 = 0.f;
#pragma unroll
        for (int n = 0; n < 4; ++n) { float v = acc[m][n][j]; s += v; s2 += v * v; }
#pragma unroll
        for (int off = 1; off < 16; off <<= 1) {
          s += __shfl_xor(s, off); s2 += __shfl_xor(s2, off);
        }
        ms[m][j] = s; m2[m][j] = s2;
      }
    if (r == 0) {
#pragma unroll
      for (int m = 0; m < 2; ++m)
#pragma unroll
        for (int j = 0; j < 4; ++j) {
          int rl = wm * 32 + m * 16 + g * 4 + j;
          rsm[wn][rl] = ms[m][j]; rs2m[wn][rl] = m2[m][j];
        }
    }
    __syncthreads();
    const float* gv = (bn < 2048) ? qg : kg;
#pragma unroll
    for (int m = 0; m < 2; ++m)
#pragma unroll
      for (int j = 0; j < 4; ++j) {
        int rl = wm * 32 + m * 16 + g * 4 + j;
        float s = rsm[0][rl] + rsm[1][rl];
        float s2 = rs2m[0][rl] + rs2m[1][rl];
        float mean = s * (1.f / 128.f);
        float var = s2 * (1.f / 128.f) - mean * mean;
        float rstd = rsqrtf(var + LN_EPS);
        int srow = bm + rl;
#pragma unroll
        for (int n = 0; n < 4; ++n) {
          int cl = wn * 64 + n * 16 + r;
          float v = (acc[m][n][j] - mean) * rstd * gv[cl];
          if (bn < 2048) qb[(size_t)srow * 2048 + bn + cl] = f2bf(v);
          else kb[(size_t)srow * 256 + (bn - 2048) + cl] = f2bf(v);
        }
      }
  }
}

// ---------------- Flash attention v3: split K/V waits (proven) -----------
__global__ __launch_bounds__(256)
void attn_fwd3(const short* __restrict__ qbuf, const short* __restrict__ kbuf,
               const short* __restrict__ vtb, short* __restrict__ obuf) {
  __shared__ short Qs[64 * 128];
  __shared__ short Ks[64 * 128];
  __shared__ short Vt[128 * 64];
  __shared__ short Ps[4][16][88];
  const int tid = threadIdx.x;
  int lin = blockIdx.x + blockIdx.y * gridDim.x;
  int sw = (lin & 7) * 32 + (lin >> 3);
  const int pair = sw & 15;
  const int h = sw >> 4;
  const int kh = h >> 3;
  const int wave = tid >> 6, lane = tid & 63;
  const int g = lane >> 4, r = lane & 15;
  const float scale = 0.08838834764831845f;

#pragma unroll
  for (int half = 0; half < 2; ++half) {
    const int qt = half ? (31 - pair) : pair;
    const int qbase = qt * 64;
    __builtin_amdgcn_s_barrier();
#pragma unroll
    for (int i = 0; i < 4; ++i) {
      int c = i * 256 + tid;
      int row = c >> 4;
      int scol = (((c & 15) ^ (row & 7)) << 3);
      glds16(qbuf + (size_t)(qbase + row) * DMODEL + h * DHEAD + scol,
             &Qs[(i * 256 + (wave << 6)) << 3]);
    }
    f32x4 O[8] = {};
    float mst[4], lst[4];
#pragma unroll
    for (int j = 0; j < 4; ++j) { mst[j] = -1e30f; lst[j] = 0.f; }
    s16x8 aq[4];

    for (int jt = 0; jt <= qt; ++jt) {
      const int jb = jt * 64;
      if (jt) __builtin_amdgcn_s_barrier();
#pragma unroll
      for (int i = 0; i < 4; ++i) {
        int c = i * 256 + tid;
        int row = c >> 4;
        int scol = (((c & 15) ^ (row & 7)) << 3);
        glds16(kbuf + (size_t)(jb + row) * 256 + kh * DHEAD + scol,
               &Ks[(i * 256 + (wave << 6)) << 3]);
      }
#pragma unroll
      for (int i = 0; i < 4; ++i) {
        int c = i * 256 + tid;
        int row = c >> 3;
        int scol = (((c & 7) ^ (row & 7)) << 3);
        glds16(vtb + (size_t)(kh * 128 + row) * S_LEN + jb + scol,
               &Vt[(i * 256 + (wave << 6)) << 3]);
      }
      asm volatile("s_waitcnt vmcnt(4)" ::: "memory");
      __builtin_amdgcn_s_barrier();
      if (jt == 0) {
#pragma unroll
        for (int kc = 0; kc < 4; ++kc) {
          int rr = wave * 16 + r;
          aq[kc] = *(const s16x8*)&Qs[rr * 128 + ((((kc << 2) | g) ^ (rr & 7)) << 3)];
        }
      }
      f32x4 sc[4] = {};
      __builtin_amdgcn_s_setprio(1);
#pragma unroll
      for (int n = 0; n < 4; ++n) {
        int rr = n * 16 + r;
#pragma unroll
        for (int kc = 0; kc < 4; ++kc) {
          s16x8 bk = *(const s16x8*)&Ks[rr * 128 + ((((kc << 2) | g) ^ (rr & 7)) << 3)];
          sc[n] = __builtin_amdgcn_mfma_f32_16x16x32_bf16(aq[kc], bk, sc[n], 0, 0, 0);
        }
      }
      __builtin_amdgcn_s_setprio(0);
      if (jt == qt) {
#pragma unroll
        for (int j = 0; j < 4; ++j) {
          int irow = qbase + wave * 16 + g * 4 + j;
#pragma unroll
          for (int n = 0; n < 4; ++n) {
            int jcol = jb + n * 16 + r;
            sc[n][j] = (jcol <= irow) ? sc[n][j] * scale : -1e30f;
          }
        }
      } else {
#pragma unroll
        for (int j = 0; j < 4; ++j)
#pragma unroll
          for (int n = 0; n < 4; ++n) sc[n][j] *= scale;
      }
      float pmax[4], alpha[4], rsum[4];
#pragma unroll
      for (int j = 0; j < 4; ++j)
        pmax[j] = fmaxf(fmaxf(sc[0][j], sc[1][j]), fmaxf(sc[2][j], sc[3][j]));
#pragma unroll
      for (int off = 1; off < 16; off <<= 1)
#pragma unroll
        for (int j = 0; j < 4; ++j) pmax[j] = fmaxf(pmax[j], __shfl_xor(pmax[j], off));
#pragma unroll
      for (int j = 0; j < 4; ++j) {
        float mnew = fmaxf(mst[j], pmax[j]);
        alpha[j] = __expf(mst[j] - mnew);
        mst[j] = mnew;
#pragma unroll
        for (int n = 0; n < 4; ++n) sc[n][j] = __expf(sc[n][j] - mnew);
        rsum[j] = (sc[0][j] + sc[1][j]) + (sc[2][j] + sc[3][j]);
      }
#pragma unroll
      for (int off = 1; off < 16; off <<= 1)
#pragma unroll
        for (int j = 0; j < 4; ++j) rsum[j] += __shfl_xor(rsum[j], off);
#pragma unroll
      for (int j = 0; j < 4; ++j) lst[j] = lst[j] * alpha[j] + rsum[j];
#pragma unroll
      for (int d = 0; d < 8; ++d)
#pragma unroll
        for (int j = 0; j < 4; ++j) O[d][j] *= alpha[j];
      asm volatile("s_waitcnt vmcnt(0)" ::: "memory");
      __builtin_amdgcn_s_barrier();
#pragma unroll
      for (int j = 0; j < 4; ++j)
#pragma unroll
        for (int n = 0; n < 4; ++n)
          Ps[wave][g * 4 + j][n * 16 + r] = f2bf(sc[n][j]);
      s16x8 pa0 = *(const s16x8*)&Ps[wave][r][g * 8];
      s16x8 pa1 = *(const s16x8*)&Ps[wave][r][32 + g * 8];
      __builtin_amdgcn_s_setprio(1);
#pragma unroll
      for (int d = 0; d < 8; ++d) {
        int dd = d * 16 + r;
        s16x8 b0 = *(const s16x8*)&Vt[dd * 64 + ((g ^ (dd & 7)) << 3)];
        s16x8 b1 = *(const s16x8*)&Vt[dd * 64 + (((4 + g) ^ (dd & 7)) << 3)];
        O[d] = __builtin_amdgcn_mfma_f32_16x16x32_bf16(pa0, b0, O[d], 0, 0, 0);
        O[d] = __builtin_amdgcn_mfma_f32_16x16x32_bf16(pa1, b1, O[d], 0, 0, 0);
      }
      __builtin_amdgcn_s_setprio(0);
    }
    float linv[4];
#pragma unroll
    for (int j = 0; j < 4; ++j) linv[j] = 1.f / lst[j];
#pragma unroll
    for (int d = 0; d < 8; ++d)
#pragma unroll
      for (int j = 0; j < 4; ++j)
        obuf[(size_t)(qbase + wave * 16 + g * 4 + j) * DMODEL + h * DHEAD + d * 16 + r] =
            f2bf(O[d][j] * linv[j]);
  }
}

// ---------------- host side ----------------
extern "C" void kernel_launch(void* const* d_in, const int* in_sizes, int n_in,
                              void* d_out, int out_size, void* d_ws, size_t ws_size,
                              hipStream_t stream) {
  const int* text = (const int*)d_in[0];
  const float* embed_w = (const float*)d_in[1];
  const float* model_g = (const float*)d_in[2];
  const float* model_b = (const float*)d_in[3];
  const float* blk_g = (const float*)d_in[4];
  const float* blk_b = (const float*)d_in[5];
  const float* attn_g = (const float*)d_in[6];
  const float* attn_b = (const float*)d_in[7];
  const float* wq = (const float*)d_in[8];
  const float* wk = (const float*)d_in[9];
  const float* wv = (const float*)d_in[10];
  const float* wo = (const float*)d_in[11];
  const float* qn_g = (const float*)d_in[12];
  const float* kn_g = (const float*)d_in[13];
  const float* w1 = (const float*)d_in[14];
  const float* b1 = (const float*)d_in[15];
  const float* w2 = (const float*)d_in[16];
  const float* b2 = (const float*)d_in[17];
  const float* head_g = (const float*)d_in[18];
  const float* head_b = (const float*)d_in[19];
  const float* head_w = (const float*)d_in[20];
  const float* head_bias = (const float*)d_in[21];
  float* out = (float*)d_out;

  const size_t SD = (size_t)S_LEN * DMODEL;
  const size_t SKV = (size_t)S_LEN * KVHEAD * DHEAD;
  const size_t SI = (size_t)S_LEN * INNER_DIM;
  const size_t WD = (size_t)DMODEL * DMODEL;
  const size_t WKV = (size_t)DMODEL * KVHEAD * DHEAD;
  const size_t WI = (size_t)DMODEL * INNER_DIM;

  char* p = (char*)d_ws;
  float* wpart = (float*)p; p += SD * 4 * 2;
  short* hb16  = (short*)p; p += SD * 2;
  short* hn16  = (short*)p; p += SD * 2;
  short* h216  = (short*)p; p += SD * 2;
  short* ao16  = (short*)p; p += SD * 2;
  short* ffi16 = (short*)p; p += SI * 2;
  short* qb16  = (short*)p; p += SD * 2;
  short* kb16  = (short*)p; p += SKV * 2;
  short* vt16  = (short*)p; p += SKV * 2;
  short* wqkvT = (short*)p; p += (size_t)QKVN * DMODEL * 2;
  short* woT   = (short*)p; p += WD * 2;
  short* w1T   = (short*)p; p += WI * 2;
  short* w2T   = (short*)p; p += WI * 2;
  short* headT = w1T;

  dim3 blk(256);
  embed_ln3<<<S_LEN, blk, 0, stream>>>(text, embed_w, model_g, model_b,
                                       blk_g, blk_b, attn_g, attn_b, hb16, hn16);

  for (int i = 0; i < NLAYER; ++i) {
    wtrans_all<<<10496, blk, 0, stream>>>(
        wq + (size_t)i * WD, wk + (size_t)i * WKV, wv + (size_t)i * WKV,
        wo + (size_t)i * WD, w1 + (size_t)i * WI, w2 + (size_t)i * WI,
        wqkvT, woT, w1T, w2T);

    // qkv: 64x128 tiles -> 640 blocks (2-3 resident/CU)
    gemm_qkv<<<dim3(QKVN / 128, S_LEN / 64), blk, 0, stream>>>(
        hn16, wqkvT, qn_g + i * DHEAD, kn_g + i * DHEAD,
        qb16, kb16, vt16, S_LEN, DMODEL);

    attn_fwd3<<<dim3(16, 16), blk, 0, stream>>>(qb16, kb16, vt16, ao16);

    // h2(bf16) = ao @ wo + hb16 : 64x128 tiles -> 512 blocks
    gemm_db<64, 128, 64, 2, 2, 0, false, true, false, true, false>
        <<<dim3(DMODEL / 128, S_LEN / 64), blk, 0, stream>>>(
        ao16, woT, nullptr, hb16, nullptr, h216,
        S_LEN, DMODEL, DMODEL, DMODEL, DMODEL);
    // ffi = gelu(h2 @ w1 + b1): 128^2 -> 1024 blocks
    gemm_db<128, 128, 64, 2, 2, 1, true, false, false, true, false>
        <<<dim3(INNER_DIM / 128, S_LEN / 128), blk, 0, stream>>>(
        h216, w1T, b1 + (size_t)i * INNER_DIM, nullptr, nullptr, ffi16,
        S_LEN, INNER_DIM, DMODEL, DMODEL, DMODEL);
    // w2: split-K x2 -> 512 blocks; partials reduced in fused LN
    gemm_db<128, 128, 64, 2, 2, 0, false, false, true, false, true>
        <<<dim3(DMODEL / 128, S_LEN / 128, 2), blk, 0, stream>>>(
        ffi16, w2T, nullptr, nullptr, wpart, nullptr,
        S_LEN, DMODEL, INNER_DIM / 2, INNER_DIM, INNER_DIM);

    if (i + 1 < NLAYER) {
      ln_triple_sum<<<S_LEN, blk, 0, stream>>>(
          wpart, wpart + SD, h216, b2 + (size_t)i * DMODEL,
          model_g, model_b,
          blk_g + (i + 1) * DMODEL, blk_b + (i + 1) * DMODEL,
          attn_g + (i + 1) * DMODEL, attn_b + (i + 1) * DMODEL, hb16, hn16);
    } else {
      ln_dual_sum<<<S_LEN, blk, 0, stream>>>(
          wpart, wpart + SD, h216, b2 + (size_t)i * DMODEL,
          model_g, model_b, head_g, head_b, hn16);
    }
  }

  wtrans64<<<dim3(VOCAB_PAD / 64, 32), blk, 0, stream>>>(head_w, headT, DMODEL, VOCAB, VOCAB_PAD);
  // head: 128^2 -> 1280 blocks
  gemm_db<128, 128, 64, 2, 2, 0, true, false, true, false, false>
      <<<dim3(VOCAB_PAD / 128, S_LEN / 128), blk, 0, stream>>>(
      hn16, headT, head_bias, nullptr, out, nullptr,
      S_LEN, VOCAB, DMODEL, DMODEL, DMODEL);
}